// Round 5
// baseline (607.926 us; speedup 1.0000x reference)
//
#include <hip/hip_runtime.h>

// Problem constants
#define D     1024
#define H     8
#define M     2048
#define IMG   49152          // 128*128*3
#define IMG4  12288          // IMG/4
#define NC    32             // m-chunks for out partial stage (64 m each)

typedef float nfloat4 __attribute__((ext_vector_type(4)));  // native vec for nontemporal builtins

// Workspace layout (in floats)
#define WS_Q      0          // [H*D]       = 8192
#define WS_P      8192       // [H*D]       = 8192  (atomic-accumulated, zeroed by qproj blk 0)
#define WS_LOGITS 16448      // [H*M]       = 16384
#define WS_W      32832      // [H*M]       = 16384
#define WS_PART   65536      // [NC*H*IMG]  = 12,582,912 floats (50 MB)

// ---------------------------------------------------------------------------
// Kernel A: q[h,e] = sum_d Q[d]*WQ[h,e,d] + bQ[h,e]
// One wave per (h,e). 8192 waves -> 2048 blocks of 256.
// Block 0 additionally zeroes the p accumulator (runs before pproj in stream
// order, so no race).
__global__ __launch_bounds__(256) void qproj_kernel(
    const float* __restrict__ Q, const float* __restrict__ WQ,
    const float* __restrict__ bQ, float* __restrict__ q_out,
    float* __restrict__ p_zero) {
  if (blockIdx.x == 0) {
#pragma unroll
    for (int i = 0; i < (H * D) / 256; ++i)
      p_zero[i * 256 + threadIdx.x] = 0.f;
  }
  int wave = (blockIdx.x * 256 + threadIdx.x) >> 6;
  int lane = threadIdx.x & 63;
  int h = wave >> 10;
  int e = wave & 1023;
  const float4* Wrow = (const float4*)(WQ + (size_t)(h * D + e) * D);
  const float4* Q4 = (const float4*)Q;
  float acc = 0.f;
#pragma unroll
  for (int i = 0; i < 4; ++i) {
    float4 w = Wrow[lane + i * 64];
    float4 qv = Q4[lane + i * 64];
    acc += w.x * qv.x + w.y * qv.y + w.z * qv.z + w.w * qv.w;
  }
#pragma unroll
  for (int off = 32; off; off >>= 1) acc += __shfl_xor(acc, off, 64);
  if (lane == 0) q_out[h * D + e] = acc + bQ[h * D + e];
}

// ---------------------------------------------------------------------------
// Kernel B: p[h,d] += sum_{e in chunk of 8} q[h,e] * WK[h,e,d]
// grid (128 e-chunks, 8 heads) = 1024 blocks (4/CU); thread owns 4 consecutive d.
// 1M atomics into a 32 KB L2-hot region — cheap.
__global__ __launch_bounds__(256) void pproj_kernel(
    const float* __restrict__ q, const float* __restrict__ WK,
    float* __restrict__ p) {
  int h = blockIdx.y;
  int e0 = blockIdx.x * 8;
  __shared__ float qc[8];
  if (threadIdx.x < 8) qc[threadIdx.x] = q[h * D + e0 + threadIdx.x];
  __syncthreads();
  const float4* W4 = (const float4*)(WK + (size_t)h * D * D);
  float4 acc = {0.f, 0.f, 0.f, 0.f};
#pragma unroll
  for (int ee = 0; ee < 8; ++ee) {
    float4 w = W4[(size_t)(e0 + ee) * (D / 4) + threadIdx.x];
    float qe = qc[ee];
    acc.x += qe * w.x;
    acc.y += qe * w.y;
    acc.z += qe * w.z;
    acc.w += qe * w.w;
  }
  float* pd = p + h * D + threadIdx.x * 4;
  atomicAdd(pd + 0, acc.x);
  atomicAdd(pd + 1, acc.y);
  atomicAdd(pd + 2, acc.z);
  atomicAdd(pd + 3, acc.w);
}

// ---------------------------------------------------------------------------
// Kernel C: logits[h,m] = (K[m,:] . p[h,:]) / 1024
// NOTE: the q·bK bias term is constant over m and cancels in softmax — dropped.
// One wave per m (all 8 heads together). 2048 waves -> 512 blocks of 256.
__global__ __launch_bounds__(256) void logits_kernel(
    const float* __restrict__ K, const float* __restrict__ p,
    float* __restrict__ logits) {
  int wave = (blockIdx.x * 256 + threadIdx.x) >> 6;
  int lane = threadIdx.x & 63;
  int m = wave;
  const float4* K4 = (const float4*)(K + (size_t)m * D);
  float acc[H];
#pragma unroll
  for (int h = 0; h < H; ++h) acc[h] = 0.f;
#pragma unroll
  for (int i = 0; i < 4; ++i) {
    float4 kv = K4[lane + i * 64];
#pragma unroll
    for (int h = 0; h < H; ++h) {
      float4 pv = ((const float4*)(p + h * D))[lane + i * 64];
      acc[h] += kv.x * pv.x + kv.y * pv.y + kv.z * pv.z + kv.w * pv.w;
    }
  }
#pragma unroll
  for (int h = 0; h < H; ++h) {
    float a = acc[h];
#pragma unroll
    for (int off = 32; off; off >>= 1) a += __shfl_xor(a, off, 64);
    if (lane == 0) logits[h * M + m] = a * (1.0f / (float)D);
  }
}

// ---------------------------------------------------------------------------
// Kernel D: softmax over m per head. 8 blocks of 256 (8 elements/thread).
__global__ __launch_bounds__(256) void softmax_kernel(
    const float* __restrict__ logits, float* __restrict__ w) {
  int h = blockIdx.x;
  int lane = threadIdx.x & 63;
  int wid = threadIdx.x >> 6;
  __shared__ float sred[8];
  float l[8];
  float mx = -1e30f;
#pragma unroll
  for (int i = 0; i < 8; ++i) {
    l[i] = logits[h * M + threadIdx.x + i * 256];
    mx = fmaxf(mx, l[i]);
  }
#pragma unroll
  for (int off = 32; off; off >>= 1) mx = fmaxf(mx, __shfl_xor(mx, off, 64));
  if (lane == 0) sred[wid] = mx;
  __syncthreads();
  float bmax = fmaxf(fmaxf(sred[0], sred[1]), fmaxf(sred[2], sred[3]));
  float ev[8];
  float s = 0.f;
#pragma unroll
  for (int i = 0; i < 8; ++i) {
    ev[i] = __expf(l[i] - bmax);
    s += ev[i];
  }
#pragma unroll
  for (int off = 32; off; off >>= 1) s += __shfl_xor(s, off, 64);
  if (lane == 0) sred[4 + wid] = s;
  __syncthreads();
  float tot = sred[4] + sred[5] + sred[6] + sred[7];
  float inv = 1.0f / tot;
#pragma unroll
  for (int i = 0; i < 8; ++i)
    w[h * M + threadIdx.x + i * 256] = ev[i] * inv;
}

// ---------------------------------------------------------------------------
// Kernel E1: partials[mc][h][j] = sum_{m in chunk of 64} w[h,m] * V[m,j]
// grid (48 col-blocks, NC=32 m-chunks) = 1536 blocks (6/CU, 24 waves/CU).
// NO atomics: plain nontemporal stores. m-loop unrolled x8 for loads in flight.
__global__ __launch_bounds__(256) void out_partial_kernel(
    const float* __restrict__ V, const float* __restrict__ w,
    float* __restrict__ part) {
  int mc = blockIdx.y;
  int m0 = mc * 64;
  int c4 = blockIdx.x * 256 + threadIdx.x;  // float4 column index [0, 12288)
  __shared__ float wc[H][64];
  for (int i = threadIdx.x; i < H * 64; i += 256)
    wc[i >> 6][i & 63] = w[(i >> 6) * M + m0 + (i & 63)];
  __syncthreads();
  const nfloat4* V4 = (const nfloat4*)V;
  float4 acc[H];
#pragma unroll
  for (int h = 0; h < H; ++h) acc[h] = make_float4(0.f, 0.f, 0.f, 0.f);
  for (int mm = 0; mm < 64; mm += 8) {
    nfloat4 v[8];
#pragma unroll
    for (int j = 0; j < 8; ++j)
      v[j] = __builtin_nontemporal_load(&V4[(size_t)(m0 + mm + j) * IMG4 + c4]);
#pragma unroll
    for (int h = 0; h < H; ++h) {
#pragma unroll
      for (int j = 0; j < 8; ++j) {
        float wj = wc[h][mm + j];
        acc[h].x += wj * v[j].x;
        acc[h].y += wj * v[j].y;
        acc[h].z += wj * v[j].z;
        acc[h].w += wj * v[j].w;
      }
    }
  }
  nfloat4* P4 = (nfloat4*)part;
#pragma unroll
  for (int h = 0; h < H; ++h) {
    nfloat4 o = {acc[h].x, acc[h].y, acc[h].z, acc[h].w};
    __builtin_nontemporal_store(o, &P4[((size_t)mc * H + h) * IMG4 + c4]);
  }
}

// ---------------------------------------------------------------------------
// Kernel E2: out[h][j] = sum_mc partials[mc][h][j]. 384 blocks of 256.
__global__ __launch_bounds__(256) void out_reduce_kernel(
    const float* __restrict__ part, float* __restrict__ out) {
  int idx = blockIdx.x * 256 + threadIdx.x;  // float4 index into H*IMG4 = 98304
  const nfloat4* P4 = (const nfloat4*)part;
  float4 s = make_float4(0.f, 0.f, 0.f, 0.f);
#pragma unroll
  for (int mc = 0; mc < NC; ++mc) {
    nfloat4 v = __builtin_nontemporal_load(&P4[(size_t)mc * (H * IMG4) + idx]);
    s.x += v.x; s.y += v.y; s.z += v.z; s.w += v.w;
  }
  nfloat4 o = {s.x, s.y, s.z, s.w};
  __builtin_nontemporal_store(o, &((nfloat4*)out)[idx]);
}

// ---------------------------------------------------------------------------
extern "C" void kernel_launch(void* const* d_in, const int* in_sizes, int n_in,
                              void* d_out, int out_size, void* d_ws, size_t ws_size,
                              hipStream_t stream) {
  const float* Q  = (const float*)d_in[0];
  const float* K  = (const float*)d_in[1];
  const float* V  = (const float*)d_in[2];
  const float* WQ = (const float*)d_in[3];
  const float* bQ = (const float*)d_in[4];
  const float* WK = (const float*)d_in[5];
  float* out = (float*)d_out;
  float* ws = (float*)d_ws;

  float* q_ws     = ws + WS_Q;
  float* p_ws     = ws + WS_P;
  float* log_ws   = ws + WS_LOGITS;
  float* w_ws     = ws + WS_W;
  float* part_ws  = ws + WS_PART;

  qproj_kernel<<<dim3(2048), dim3(256), 0, stream>>>(Q, WQ, bQ, q_ws, p_ws);
  pproj_kernel<<<dim3(128, H), dim3(256), 0, stream>>>(q_ws, WK, p_ws);
  logits_kernel<<<dim3(512), dim3(256), 0, stream>>>(K, p_ws, log_ws);
  softmax_kernel<<<dim3(H), dim3(256), 0, stream>>>(log_ws, w_ws);
  out_partial_kernel<<<dim3(48, NC), dim3(256), 0, stream>>>(V, w_ws, part_ws);
  out_reduce_kernel<<<dim3(384), dim3(256), 0, stream>>>(part_ws, out);
}